// Round 10
// baseline (85.255 us; speedup 1.0000x reference)
//
#include <hip/hip_runtime.h>

#define B_ 64
#define H_ 384
#define W_ 384
#define C_ 3
#define TILE 16
#define TILES_X 24            // 384/16
#define TILES_PER_IMG 576     // 24*24
#define GRID (B_ * TILES_PER_IMG)   // 36864, %8==0
#define IMG_PX (H_ * W_)
#define LDS_PX 2730           // 2730*12B = 32760B -> 4 blocks/CU (16 waves)

struct Tap { float v0, v1, v2; };   // 12B -> global_load_dwordx3

// Exact per-op-rounded f32 pipeline (numpy-replicating) — per-pixel only.
__device__ __forceinline__ void map_xy(
    int i, int j,
    float th0, float th1, float th2, float th3, float th4, float th5,
    float& x, float& y)
{
    const double STEP = 2.0 / 383.0;
    float xs = (j == W_ - 1) ? 1.0f : (float)((double)j * STEP - 1.0);
    float ys = (i == H_ - 1) ? 1.0f : (float)((double)i * STEP - 1.0);
    float t0 = __fadd_rn(__fadd_rn(__fmul_rn(th0, xs), __fmul_rn(th1, ys)), th2);
    float t1 = __fadd_rn(__fadd_rn(__fmul_rn(th3, xs), __fmul_rn(th4, ys)), th5);
    x = __fmul_rn(__fadd_rn(t0, 1.0f), (float)(W_ * 0.5));
    y = __fmul_rn(__fadd_rn(t1, 1.0f), (float)(H_ * 0.5));
}

__global__ __launch_bounds__(256, 4) void bilerp_kernel(
    const float* __restrict__ images,
    const float* __restrict__ theta,
    float* __restrict__ out)
{
    __shared__ float lds[LDS_PX * 3];

    // bijective chunked XCD swizzle (GRID % 8 == 0)
    int bid = blockIdx.x;
    int lbid = (bid & 7) * (GRID / 8) + (bid >> 3);

    int b  = lbid / TILES_PER_IMG;
    int t  = lbid - b * TILES_PER_IMG;
    int ti = t / TILES_X;
    int tj = t - ti * TILES_X;
    int i0 = ti * TILE, j0 = tj * TILE;

    int tid = threadIdx.x;
    int ty = tid >> 4, tx = tid & 15;
    int i = i0 + ty, j = j0 + tx;

    const float* th = theta + b * 6;
    float th0 = th[0], th1 = th[1], th2 = th[2];
    float th3 = th[3], th4 = th[4], th5 = th[5];
    const float* img = images + (size_t)b * (IMG_PX * C_);
    float* outb = out + (size_t)b * (IMG_PX * C_);

    // ---- fast f32 bbox from corners + safety margin (containment by
    //      affinity: extremes at corners; margin covers rounding deltas) ----
    const float STEPF = (float)(2.0 / 383.0);
    float xsl = fmaf((float)j0, STEPF, -1.0f);
    float xsh = (j0 + TILE - 1 == W_ - 1) ? 1.0f : fmaf((float)(j0 + TILE - 1), STEPF, -1.0f);
    float ysl = fmaf((float)i0, STEPF, -1.0f);
    float ysh = (i0 + TILE - 1 == H_ - 1) ? 1.0f : fmaf((float)(i0 + TILE - 1), STEPF, -1.0f);

    float xmin, xmax, ymin, ymax;
    {
        float ax_l = th0 * xsl, ax_h = th0 * xsh;
        float bx_l = th1 * ysl, bx_h = th1 * ysh;
        float ay_l = th3 * xsl, ay_h = th3 * xsh;
        float by_l = th4 * ysl, by_h = th4 * ysh;
        float cx = (th2 + 1.0f) * (W_ * 0.5f);
        float cy = (th5 + 1.0f) * (H_ * 0.5f);
        xmin = fmaf(fminf(ax_l, ax_h) + fminf(bx_l, bx_h), (float)(W_ * 0.5), cx);
        xmax = fmaf(fmaxf(ax_l, ax_h) + fmaxf(bx_l, bx_h), (float)(W_ * 0.5), cx);
        ymin = fmaf(fminf(ay_l, ay_h) + fminf(by_l, by_h), (float)(H_ * 0.5), cy);
        ymax = fmaf(fmaxf(ay_l, ay_h) + fmaxf(by_l, by_h), (float)(H_ * 0.5), cy);
    }

    int XL = min(max((int)floorf(xmin) - 2, 0), W_ - 1);
    int XH = min(max((int)floorf(xmax) + 3, 0), W_ - 1);
    int YL = min(max((int)floorf(ymin) - 2, 0), H_ - 1);
    int YH = min(max((int)floorf(ymax) + 3, 0), H_ - 1);
    int ncols = XH - XL + 1;
    int nrows = YH - YL + 1;
    int npx = ncols * nrows;

    // ---- per-pixel coords/weights (bit-identical to passing kernels) ----
    float x, y;
    map_xy(i, j, th0, th1, th2, th3, th4, th5, x, y);

    float fx = floorf(x);
    float fy = floorf(y);
    int x0 = min(max((int)fx, 0), W_ - 1);
    int x1 = min(max((int)fx + 1, 0), W_ - 1);
    int y0 = min(max((int)fy, 0), H_ - 1);
    int y1 = min(max((int)fy + 1, 0), H_ - 1);

    float xc = fminf(fmaxf(x, 0.0f), (float)(W_ - 1));
    float yc = fminf(fmaxf(y, 0.0f), (float)(H_ - 1));

    float x0f = (float)x0, x1f = (float)x1;
    float y0f = (float)y0, y1f = (float)y1;

    float wx0 = __fsub_rn(x1f, xc);
    float wx1 = __fsub_rn(xc, x0f);
    float wy0 = __fsub_rn(y1f, yc);
    float wy1 = __fsub_rn(yc, y0f);

    float wa = __fmul_rn(wx0, wy0);
    float wb = __fmul_rn(wx0, wy1);
    float wc = __fmul_rn(wx1, wy0);
    float wd = __fmul_rn(wx1, wy1);

    Tap A, Bv, Cv, D;

    if (npx <= LDS_PX) {
        // ---- staged: coalesced dwordx3 bbox load -> LDS; no int division ----
        unsigned ncols_u = (unsigned)ncols;
        unsigned npx_u = (unsigned)npx;
        double inv = 1.0 / (double)ncols;   // exact-floor trick: +0.5 never int
        unsigned p = (unsigned)tid;
        unsigned r = (unsigned)(((double)p + 0.5) * inv);
        unsigned c = p - r * ncols_u;
        unsigned dr = (unsigned)(256.5 * inv);
        unsigned dc = 256u - dr * ncols_u;
        while (p < npx_u) {
            const Tap* s = (const Tap*)(img + ((size_t)(YL + (int)r) * W_ + (XL + (int)c)) * C_);
            Tap tv = *s;
            int d = (int)p * 3;
            lds[d + 0] = tv.v0;
            lds[d + 1] = tv.v1;
            lds[d + 2] = tv.v2;
            p += 256u; c += dc; r += dr;
            if (c >= ncols_u) { c -= ncols_u; r += 1u; }
        }
        __syncthreads();

        int la = ((y0 - YL) * ncols + (x0 - XL)) * 3;
        int lb = ((y1 - YL) * ncols + (x0 - XL)) * 3;
        int lc = ((y0 - YL) * ncols + (x1 - XL)) * 3;
        int ld = ((y1 - YL) * ncols + (x1 - XL)) * 3;
        A.v0  = lds[la + 0]; A.v1  = lds[la + 1]; A.v2  = lds[la + 2];
        Bv.v0 = lds[lb + 0]; Bv.v1 = lds[lb + 1]; Bv.v2 = lds[lb + 2];
        Cv.v0 = lds[lc + 0]; Cv.v1 = lds[lc + 1]; Cv.v2 = lds[lc + 2];
        D.v0  = lds[ld + 0]; D.v1  = lds[ld + 1]; D.v2  = lds[ld + 2];
    } else {
        // ---- fallback (~5% of tiles): direct global gathers, uniform branch ----
        A  = *(const Tap*)(img + ((size_t)y0 * W_ + x0) * C_);
        Bv = *(const Tap*)(img + ((size_t)y1 * W_ + x0) * C_);
        Cv = *(const Tap*)(img + ((size_t)y0 * W_ + x1) * C_);
        D  = *(const Tap*)(img + ((size_t)y1 * W_ + x1) * C_);
    }

    // ---- weighted sum, per-op rounded f32 (identical association) ----
    float r0 = __fadd_rn(
        __fadd_rn(
            __fadd_rn(__fmul_rn(wa, A.v0), __fmul_rn(wb, Bv.v0)),
            __fmul_rn(wc, Cv.v0)),
        __fmul_rn(wd, D.v0));
    float r1 = __fadd_rn(
        __fadd_rn(
            __fadd_rn(__fmul_rn(wa, A.v1), __fmul_rn(wb, Bv.v1)),
            __fmul_rn(wc, Cv.v1)),
        __fmul_rn(wd, D.v1));
    float r2 = __fadd_rn(
        __fadd_rn(
            __fadd_rn(__fmul_rn(wa, A.v2), __fmul_rn(wb, Bv.v2)),
            __fmul_rn(wc, Cv.v2)),
        __fmul_rn(wd, D.v2));

    Tap* o = (Tap*)(outb + ((size_t)i * W_ + j) * C_);
    Tap v = { r0, r1, r2 };
    *o = v;
}

extern "C" void kernel_launch(void* const* d_in, const int* in_sizes, int n_in,
                              void* d_out, int out_size, void* d_ws, size_t ws_size,
                              hipStream_t stream) {
    const float* images = (const float*)d_in[0];
    const float* theta  = (const float*)d_in[1];
    float* out = (float*)d_out;

    bilerp_kernel<<<GRID, 256, 0, stream>>>(images, theta, out);
}

// Round 11
// 48.519 us; speedup vs baseline: 1.7571x; 1.7571x over previous
//
#include <hip/hip_runtime.h>

#define B_ 64
#define H_ 384
#define W_ 384
#define C_ 3
#define K_ 4
#define IMG_PX (H_ * W_)
#define TILES_X 12            // 384/32
#define TILES_PER_IMG 144     // 12*12
#define GRID 9216             // 64 images * 144 tiles of 32x32, %8==0

struct Tap { float v0, v1, v2; };   // 12B -> global_load_dwordx3

__global__ __launch_bounds__(256) void bilerp_kernel(
    const float* __restrict__ images,
    const float* __restrict__ theta,
    float* __restrict__ out)
{
    // bijective chunked XCD swizzle: whole images per XCD -> input L2/L3-resident
    int bid = blockIdx.x;
    int lbid = (bid & 7) * (GRID / 8) + (bid >> 3);

    int b  = lbid / TILES_PER_IMG;
    int t  = lbid - b * TILES_PER_IMG;
    int ti = t / TILES_X;
    int tj = t - ti * TILES_X;

    int wave = threadIdx.x >> 6;
    int lane = threadIdx.x & 63;
    int dy = lane >> 3;           // 8x8 lane tile: compact gather footprint
    int dx = lane & 7;

    int i_base = ti * 32 + (wave >> 1) * 16;
    int j_base = tj * 32 + (wave & 1) * 16;

    const float* th = theta + b * 6;
    float th0 = th[0], th1 = th[1], th2 = th[2];
    float th3 = th[3], th4 = th[4], th5 = th[5];
    const float* img = images + (size_t)b * (IMG_PX * C_);
    float* outb = out + (size_t)b * (IMG_PX * C_);

    const double STEP = 2.0 / 383.0;

    float wa_[K_], wb_[K_], wc_[K_], wd_[K_];
    const Tap* pa[K_]; const Tap* pb[K_]; const Tap* pc[K_]; const Tap* pd[K_];
    int pi[K_], pj[K_];

    // ---- phase 1a: ALL addresses + weights (pure VALU, no loads) ----
#pragma unroll
    for (int k = 0; k < K_; ++k) {
        int i = i_base + (k >> 1) * 8 + dy;
        int j = j_base + (k & 1) * 8 + dx;
        pi[k] = i; pj[k] = j;

        // numpy f32 linspace: f64 (k*step - 1) then cast; endpoint exact
        float xs = (j == W_ - 1) ? 1.0f : (float)((double)j * STEP - 1.0);
        float ys = (i == H_ - 1) ? 1.0f : (float)((double)i * STEP - 1.0);

        // einsum: ((th0*xs) + (th1*ys)) + th2 — per-op f32, no contraction
        float t0 = __fadd_rn(__fadd_rn(__fmul_rn(th0, xs), __fmul_rn(th1, ys)), th2);
        float t1 = __fadd_rn(__fadd_rn(__fmul_rn(th3, xs), __fmul_rn(th4, ys)), th5);

        float x = __fmul_rn(__fadd_rn(t0, 1.0f), (float)(W_ * 0.5));
        float y = __fmul_rn(__fadd_rn(t1, 1.0f), (float)(H_ * 0.5));

        float fx = floorf(x);
        float fy = floorf(y);
        int x0 = min(max((int)fx, 0), W_ - 1);
        int x1 = min(max((int)fx + 1, 0), W_ - 1);
        int y0 = min(max((int)fy, 0), H_ - 1);
        int y1 = min(max((int)fy + 1, 0), H_ - 1);

        float xc = fminf(fmaxf(x, 0.0f), (float)(W_ - 1));
        float yc = fminf(fmaxf(y, 0.0f), (float)(H_ - 1));

        float x0f = (float)x0, x1f = (float)x1;
        float y0f = (float)y0, y1f = (float)y1;

        float wx0 = __fsub_rn(x1f, xc);
        float wx1 = __fsub_rn(xc, x0f);
        float wy0 = __fsub_rn(y1f, yc);
        float wy1 = __fsub_rn(yc, y0f);

        wa_[k] = __fmul_rn(wx0, wy0);
        wb_[k] = __fmul_rn(wx0, wy1);
        wc_[k] = __fmul_rn(wx1, wy0);
        wd_[k] = __fmul_rn(wx1, wy1);

        pa[k] = (const Tap*)(img + (y0 * W_ + x0) * C_);
        pb[k] = (const Tap*)(img + (y1 * W_ + x0) * C_);
        pc[k] = (const Tap*)(img + (y0 * W_ + x1) * C_);
        pd[k] = (const Tap*)(img + (y1 * W_ + x1) * C_);
    }

    // ---- phase 1b: issue ALL 16 loads back-to-back ----
    Tap ta[K_], tb[K_], tc[K_], td[K_];
#pragma unroll
    for (int k = 0; k < K_; ++k) {
        ta[k] = *pa[k];
        tb[k] = *pb[k];
        tc[k] = *pc[k];
        td[k] = *pd[k];
    }

    // ---- phase 2: weighted sums (per-op rounded f32) + stores ----
#pragma unroll
    for (int k = 0; k < K_; ++k) {
        float r0 = __fadd_rn(
            __fadd_rn(
                __fadd_rn(__fmul_rn(wa_[k], ta[k].v0), __fmul_rn(wb_[k], tb[k].v0)),
                __fmul_rn(wc_[k], tc[k].v0)),
            __fmul_rn(wd_[k], td[k].v0));
        float r1 = __fadd_rn(
            __fadd_rn(
                __fadd_rn(__fmul_rn(wa_[k], ta[k].v1), __fmul_rn(wb_[k], tb[k].v1)),
                __fmul_rn(wc_[k], tc[k].v1)),
            __fmul_rn(wd_[k], td[k].v1));
        float r2 = __fadd_rn(
            __fadd_rn(
                __fadd_rn(__fmul_rn(wa_[k], ta[k].v2), __fmul_rn(wb_[k], tb[k].v2)),
                __fmul_rn(wc_[k], tc[k].v2)),
            __fmul_rn(wd_[k], td[k].v2));

        Tap* o = (Tap*)(outb + ((size_t)pi[k] * W_ + pj[k]) * C_);
        Tap v = { r0, r1, r2 };
        *o = v;
    }
}

extern "C" void kernel_launch(void* const* d_in, const int* in_sizes, int n_in,
                              void* d_out, int out_size, void* d_ws, size_t ws_size,
                              hipStream_t stream) {
    const float* images = (const float*)d_in[0];
    const float* theta  = (const float*)d_in[1];
    float* out = (float*)d_out;

    bilerp_kernel<<<GRID, 256, 0, stream>>>(images, theta, out);
}

// Round 12
// 35.332 us; speedup vs baseline: 2.4130x; 1.3733x over previous
//
#include <hip/hip_runtime.h>

#define B_ 64
#define H_ 384
#define W_ 384
#define C_ 3
#define K_ 4
#define IMG_PX (H_ * W_)
#define TILES_X 12            // 384/32
#define TILES_PER_IMG 144     // 12*12
#define GRID 9216             // 64 images * 144 tiles of 32x32, %8==0

struct Tap { float v0, v1, v2; };   // 12B -> global_load_dwordx3

__global__ __launch_bounds__(256) void bilerp_kernel(
    const float* __restrict__ images,
    const float* __restrict__ theta,
    float* __restrict__ out)
{
    // bijective chunked XCD swizzle: whole images per XCD -> input L2/L3-resident
    int bid = blockIdx.x;
    int lbid = (bid & 7) * (GRID / 8) + (bid >> 3);

    int b  = lbid / TILES_PER_IMG;
    int t  = lbid - b * TILES_PER_IMG;
    int ti = t / TILES_X;
    int tj = t - ti * TILES_X;

    int wave = threadIdx.x >> 6;
    int lane = threadIdx.x & 63;
    int dy = lane >> 3;           // 8x8 lane tile: compact footprint + uniform OOB
    int dx = lane & 7;

    int i_base = ti * 32 + (wave >> 1) * 16;
    int j_base = tj * 32 + (wave & 1) * 16;

    const float* th = theta + b * 6;
    float th0 = th[0], th1 = th[1], th2 = th[2];
    float th3 = th[3], th4 = th[4], th5 = th[5];
    const float* img = images + (size_t)b * (IMG_PX * C_);
    float* outb = out + (size_t)b * (IMG_PX * C_);

    const double STEP = 2.0 / 383.0;

    float wa_[K_], wb_[K_], wc_[K_], wd_[K_];
    const Tap* pa[K_]; const Tap* pb[K_]; const Tap* pc[K_]; const Tap* pd[K_];
    int pi[K_], pj[K_];
    bool nz[K_];

    // ---- phase 1a: ALL addresses + weights + zero-predicate (pure VALU) ----
#pragma unroll
    for (int k = 0; k < K_; ++k) {
        int i = i_base + (k >> 1) * 8 + dy;
        int j = j_base + (k & 1) * 8 + dx;
        pi[k] = i; pj[k] = j;

        // numpy f32 linspace: f64 (k*step - 1) then cast; endpoint exact
        float xs = (j == W_ - 1) ? 1.0f : (float)((double)j * STEP - 1.0);
        float ys = (i == H_ - 1) ? 1.0f : (float)((double)i * STEP - 1.0);

        // einsum: ((th0*xs) + (th1*ys)) + th2 — per-op f32, no contraction
        float t0 = __fadd_rn(__fadd_rn(__fmul_rn(th0, xs), __fmul_rn(th1, ys)), th2);
        float t1 = __fadd_rn(__fadd_rn(__fmul_rn(th3, xs), __fmul_rn(th4, ys)), th5);

        float x = __fmul_rn(__fadd_rn(t0, 1.0f), (float)(W_ * 0.5));
        float y = __fmul_rn(__fadd_rn(t1, 1.0f), (float)(H_ * 0.5));

        float fx = floorf(x);
        float fy = floorf(y);

        // all-four-weights-zero predicate: clip collapses x0==x1 (or y0==y1)
        // whenever floor(x) not in [0,382] (resp. y). Output is exactly +/-0.
        nz[k] = (fx >= 0.0f) && (fx <= 382.0f) && (fy >= 0.0f) && (fy <= 382.0f);

        int x0 = min(max((int)fx, 0), W_ - 1);
        int x1 = min(max((int)fx + 1, 0), W_ - 1);
        int y0 = min(max((int)fy, 0), H_ - 1);
        int y1 = min(max((int)fy + 1, 0), H_ - 1);

        float xc = fminf(fmaxf(x, 0.0f), (float)(W_ - 1));
        float yc = fminf(fmaxf(y, 0.0f), (float)(H_ - 1));

        float x0f = (float)x0, x1f = (float)x1;
        float y0f = (float)y0, y1f = (float)y1;

        float wx0 = __fsub_rn(x1f, xc);
        float wx1 = __fsub_rn(xc, x0f);
        float wy0 = __fsub_rn(y1f, yc);
        float wy1 = __fsub_rn(yc, y0f);

        wa_[k] = __fmul_rn(wx0, wy0);
        wb_[k] = __fmul_rn(wx0, wy1);
        wc_[k] = __fmul_rn(wx1, wy0);
        wd_[k] = __fmul_rn(wx1, wy1);

        pa[k] = (const Tap*)(img + (y0 * W_ + x0) * C_);
        pb[k] = (const Tap*)(img + (y1 * W_ + x0) * C_);
        pc[k] = (const Tap*)(img + (y0 * W_ + x1) * C_);
        pd[k] = (const Tap*)(img + (y1 * W_ + x1) * C_);
    }

    // ---- phase 1b: gathers only where weights can be nonzero ----
    Tap ta[K_], tb[K_], tc[K_], td[K_];
#pragma unroll
    for (int k = 0; k < K_; ++k) {
        if (nz[k]) {
            ta[k] = *pa[k];
            tb[k] = *pb[k];
            tc[k] = *pc[k];
            td[k] = *pd[k];
        } else {
            ta[k] = Tap{0.f, 0.f, 0.f};
            tb[k] = Tap{0.f, 0.f, 0.f};
            tc[k] = Tap{0.f, 0.f, 0.f};
            td[k] = Tap{0.f, 0.f, 0.f};
        }
    }

    // ---- phase 2: weighted sums (per-op rounded f32) + stores ----
    // For nz px this is bit-identical to the passing kernels. For OOB px all
    // four weights are exactly 0 -> result is +/-0; |0-(-0)| = 0 in absmax.
#pragma unroll
    for (int k = 0; k < K_; ++k) {
        float r0 = __fadd_rn(
            __fadd_rn(
                __fadd_rn(__fmul_rn(wa_[k], ta[k].v0), __fmul_rn(wb_[k], tb[k].v0)),
                __fmul_rn(wc_[k], tc[k].v0)),
            __fmul_rn(wd_[k], td[k].v0));
        float r1 = __fadd_rn(
            __fadd_rn(
                __fadd_rn(__fmul_rn(wa_[k], ta[k].v1), __fmul_rn(wb_[k], tb[k].v1)),
                __fmul_rn(wc_[k], tc[k].v1)),
            __fmul_rn(wd_[k], td[k].v1));
        float r2 = __fadd_rn(
            __fadd_rn(
                __fadd_rn(__fmul_rn(wa_[k], ta[k].v2), __fmul_rn(wb_[k], tb[k].v2)),
                __fmul_rn(wc_[k], tc[k].v2)),
            __fmul_rn(wd_[k], td[k].v2));

        Tap* o = (Tap*)(outb + ((size_t)pi[k] * W_ + pj[k]) * C_);
        Tap v = { r0, r1, r2 };
        *o = v;
    }
}

extern "C" void kernel_launch(void* const* d_in, const int* in_sizes, int n_in,
                              void* d_out, int out_size, void* d_ws, size_t ws_size,
                              hipStream_t stream) {
    const float* images = (const float*)d_in[0];
    const float* theta  = (const float*)d_in[1];
    float* out = (float*)d_out;

    bilerp_kernel<<<GRID, 256, 0, stream>>>(images, theta, out);
}

// Round 13
// 32.550 us; speedup vs baseline: 2.6192x; 1.0855x over previous
//
#include <hip/hip_runtime.h>

#define B_ 64
#define H_ 384
#define W_ 384
#define C_ 3
#define K_ 4
#define IMG_PX (H_ * W_)
#define TILES_X 12            // 384/32
#define TILES_PER_IMG 144     // 12*12
#define GRID 9216             // 64 images * 144 tiles of 32x32

struct Tap { float v0, v1, v2; };   // 12B -> global_load_dwordx3

__global__ __launch_bounds__(256) void bilerp_kernel(
    const float* __restrict__ images,
    const float* __restrict__ theta,
    float* __restrict__ out)
{
    // IDENTITY block mapping: consecutive blocks round-robin the 8 XCDs, so
    // each image's 144 tiles spread evenly across XCDs -> per-XCD gather work
    // is balanced regardless of per-image in-bounds fraction. Input locality
    // is carried by the die-level L3 (113MB resident), not per-XCD L2.
    int lbid = blockIdx.x;

    int b  = lbid / TILES_PER_IMG;
    int t  = lbid - b * TILES_PER_IMG;
    int ti = t / TILES_X;
    int tj = t - ti * TILES_X;

    int wave = threadIdx.x >> 6;
    int lane = threadIdx.x & 63;
    int dy = lane >> 3;           // 8x8 lane tile: compact footprint + uniform OOB
    int dx = lane & 7;

    int i_base = ti * 32 + (wave >> 1) * 16;
    int j_base = tj * 32 + (wave & 1) * 16;

    const float* th = theta + b * 6;
    float th0 = th[0], th1 = th[1], th2 = th[2];
    float th3 = th[3], th4 = th[4], th5 = th[5];
    const float* img = images + (size_t)b * (IMG_PX * C_);
    float* outb = out + (size_t)b * (IMG_PX * C_);

    const double STEP = 2.0 / 383.0;

    float wa_[K_], wb_[K_], wc_[K_], wd_[K_];
    const Tap* pa[K_]; const Tap* pb[K_]; const Tap* pc[K_]; const Tap* pd[K_];
    int pi[K_], pj[K_];
    bool nz[K_];

    // ---- phase 1a: ALL addresses + weights + zero-predicate (pure VALU) ----
#pragma unroll
    for (int k = 0; k < K_; ++k) {
        int i = i_base + (k >> 1) * 8 + dy;
        int j = j_base + (k & 1) * 8 + dx;
        pi[k] = i; pj[k] = j;

        // numpy f32 linspace: f64 (k*step - 1) then cast; endpoint exact
        float xs = (j == W_ - 1) ? 1.0f : (float)((double)j * STEP - 1.0);
        float ys = (i == H_ - 1) ? 1.0f : (float)((double)i * STEP - 1.0);

        // einsum: ((th0*xs) + (th1*ys)) + th2 — per-op f32, no contraction
        float t0 = __fadd_rn(__fadd_rn(__fmul_rn(th0, xs), __fmul_rn(th1, ys)), th2);
        float t1 = __fadd_rn(__fadd_rn(__fmul_rn(th3, xs), __fmul_rn(th4, ys)), th5);

        float x = __fmul_rn(__fadd_rn(t0, 1.0f), (float)(W_ * 0.5));
        float y = __fmul_rn(__fadd_rn(t1, 1.0f), (float)(H_ * 0.5));

        float fx = floorf(x);
        float fy = floorf(y);

        // all-four-weights-zero predicate: clip collapses x0==x1 (or y0==y1)
        // whenever floor(x) not in [0,382] (resp. y). Output is exactly +/-0.
        nz[k] = (fx >= 0.0f) && (fx <= 382.0f) && (fy >= 0.0f) && (fy <= 382.0f);

        int x0 = min(max((int)fx, 0), W_ - 1);
        int x1 = min(max((int)fx + 1, 0), W_ - 1);
        int y0 = min(max((int)fy, 0), H_ - 1);
        int y1 = min(max((int)fy + 1, 0), H_ - 1);

        float xc = fminf(fmaxf(x, 0.0f), (float)(W_ - 1));
        float yc = fminf(fmaxf(y, 0.0f), (float)(H_ - 1));

        float x0f = (float)x0, x1f = (float)x1;
        float y0f = (float)y0, y1f = (float)y1;

        float wx0 = __fsub_rn(x1f, xc);
        float wx1 = __fsub_rn(xc, x0f);
        float wy0 = __fsub_rn(y1f, yc);
        float wy1 = __fsub_rn(yc, y0f);

        wa_[k] = __fmul_rn(wx0, wy0);
        wb_[k] = __fmul_rn(wx0, wy1);
        wc_[k] = __fmul_rn(wx1, wy0);
        wd_[k] = __fmul_rn(wx1, wy1);

        pa[k] = (const Tap*)(img + (y0 * W_ + x0) * C_);
        pb[k] = (const Tap*)(img + (y1 * W_ + x0) * C_);
        pc[k] = (const Tap*)(img + (y0 * W_ + x1) * C_);
        pd[k] = (const Tap*)(img + (y1 * W_ + x1) * C_);
    }

    // ---- phase 1b: gathers only where weights can be nonzero ----
    Tap ta[K_], tb[K_], tc[K_], td[K_];
#pragma unroll
    for (int k = 0; k < K_; ++k) {
        if (nz[k]) {
            ta[k] = *pa[k];
            tb[k] = *pb[k];
            tc[k] = *pc[k];
            td[k] = *pd[k];
        } else {
            ta[k] = Tap{0.f, 0.f, 0.f};
            tb[k] = Tap{0.f, 0.f, 0.f};
            tc[k] = Tap{0.f, 0.f, 0.f};
            td[k] = Tap{0.f, 0.f, 0.f};
        }
    }

    // ---- phase 2: weighted sums (per-op rounded f32) + stores ----
    // For nz px this is bit-identical to the passing kernels. For OOB px all
    // four weights are exactly 0 -> result is +/-0; |0-(-0)| = 0 in absmax.
#pragma unroll
    for (int k = 0; k < K_; ++k) {
        float r0 = __fadd_rn(
            __fadd_rn(
                __fadd_rn(__fmul_rn(wa_[k], ta[k].v0), __fmul_rn(wb_[k], tb[k].v0)),
                __fmul_rn(wc_[k], tc[k].v0)),
            __fmul_rn(wd_[k], td[k].v0));
        float r1 = __fadd_rn(
            __fadd_rn(
                __fadd_rn(__fmul_rn(wa_[k], ta[k].v1), __fmul_rn(wb_[k], tb[k].v1)),
                __fmul_rn(wc_[k], tc[k].v1)),
            __fmul_rn(wd_[k], td[k].v1));
        float r2 = __fadd_rn(
            __fadd_rn(
                __fadd_rn(__fmul_rn(wa_[k], ta[k].v2), __fmul_rn(wb_[k], tb[k].v2)),
                __fmul_rn(wc_[k], tc[k].v2)),
            __fmul_rn(wd_[k], td[k].v2));

        Tap* o = (Tap*)(outb + ((size_t)pi[k] * W_ + pj[k]) * C_);
        Tap v = { r0, r1, r2 };
        *o = v;
    }
}

extern "C" void kernel_launch(void* const* d_in, const int* in_sizes, int n_in,
                              void* d_out, int out_size, void* d_ws, size_t ws_size,
                              hipStream_t stream) {
    const float* images = (const float*)d_in[0];
    const float* theta  = (const float*)d_in[1];
    float* out = (float*)d_out;

    bilerp_kernel<<<GRID, 256, 0, stream>>>(images, theta, out);
}